// Round 3
// baseline (169.233 us; speedup 1.0000x reference)
//
#include <hip/hip_runtime.h>

// Problem constants: B=64, T=8192, L=64, NWIN=8128
// One block per batch: 64 blocks x 1024 threads. Whole x-row staged in LDS
// (32 KB, XOR-swizzled float4 layout), each thread evaluates 8 consecutive
// windows with the j-dimension CHUNKED by 8 so the live register set stays
// ~50 VGPRs (round-2 post-mortem: the 80+64-float register caches spilled —
// VGPR_Count=128 vs ~150 live, WRITE_SIZE showed 16.6 MB of scratch stores).
// Block min-reduce on packed (dist,idx) u64 keys, same block gathers the
// winning window. No workspace, no atomics, single launch.
constexpr int B_SZ = 64;
constexpr int T_SZ = 8192;
constexpr int L_SZ = 64;
constexpr int NWIN = T_SZ - L_SZ;    // 8128
constexpr int NTHR = 1024;
constexpr int WPT  = 8;              // 1016 active threads * 8 = 8128 windows
constexpr int NJC  = L_SZ / 8;       // 8 j-chunks of 8

// XOR swizzle on float4 index: involution (same map on store and load),
// spreads strided ds_read_b128 across the 16B bank-slots.
__device__ __forceinline__ int swz(int i) { return i ^ ((i >> 3) & 7); }

__global__ __launch_bounds__(NTHR, 4)
void window_match_one(const float* __restrict__ X_in,
                      const float* __restrict__ X_out,
                      float* __restrict__ out)
{
    __shared__ float xs[T_SZ];                 // 32 KB, swizzled float4 layout
    __shared__ float ysh[L_SZ];
    __shared__ unsigned long long wred[NTHR / 64];
    __shared__ int s_win;

    const int b   = blockIdx.x;
    const int tid = threadIdx.x;

    // Stage full row: 2048 float4 over 1024 threads = 2 rounds.
    // Global side linear/coalesced; LDS side permuted by swz.
    const float4* xg  = reinterpret_cast<const float4*>(X_in + (size_t)b * T_SZ);
    float4*       xs4 = reinterpret_cast<float4*>(xs);
    #pragma unroll
    for (int r = 0; r < T_SZ / 4 / NTHR; ++r) {      // 2 rounds
        const int i = tid + r * NTHR;
        xs4[swz(i)] = xg[i];
    }
    if (tid < L_SZ) ysh[tid] = X_out[(size_t)b * L_SZ + tid];
    __syncthreads();

    unsigned long long best = ~0ull;
    const int s0 = WPT * tid;                        // first window of this thread
    if (s0 < NWIN) {                                 // tid < 1016
        float acc[WPT];
        #pragma unroll
        for (int w = 0; w < WPT; ++w) acc[w] = 0.0f;

        const float4* xr = reinterpret_cast<const float4*>(xs);
        const int f0 = 2 * tid;                      // float4 index of s0 (s0/4)

        // j chunked by 8: per chunk, 2 broadcast y reads (free) + 4 swizzled
        // b128 x reads covering xs[s0+8*jc .. s0+8*jc+15] (need +14).
        // Live set per chunk: acc[8] + xv[16] + yv[8] ≈ 32 floats.
        #pragma unroll
        for (int jc = 0; jc < NJC; ++jc) {
            float yv[8];
            {
                const float4 a = reinterpret_cast<const float4*>(ysh)[2 * jc + 0];
                const float4 c = reinterpret_cast<const float4*>(ysh)[2 * jc + 1];
                yv[0] = a.x; yv[1] = a.y; yv[2] = a.z; yv[3] = a.w;
                yv[4] = c.x; yv[5] = c.y; yv[6] = c.z; yv[7] = c.w;
            }
            float xv[16];
            #pragma unroll
            for (int k = 0; k < 4; ++k) {
                const float4 v = xr[swz(f0 + 2 * jc + k)];
                xv[4 * k + 0] = v.x;
                xv[4 * k + 1] = v.y;
                xv[4 * k + 2] = v.z;
                xv[4 * k + 3] = v.w;
            }
            #pragma unroll
            for (int w = 0; w < WPT; ++w) {
                #pragma unroll
                for (int j2 = 0; j2 < 8; ++j2) {
                    const float t = xv[w + j2] - yv[j2];   // index 0..14, static
                    acc[w] = fmaf(t, t, acc[w]);
                }
            }
        }

        // Packed key: ((float_bits(d)<<32)|idx) — d>=0 so u64 order ==
        // (dist, idx) lexicographic, ties -> smallest index == np.argmin.
        #pragma unroll
        for (int w = 0; w < WPT; ++w) {
            const unsigned long long key =
                ((unsigned long long)__float_as_uint(acc[w]) << 32) |
                (unsigned int)(s0 + w);
            best = key < best ? key : best;
        }
    }

    // Wave (64-lane) shuffle reduce, then cross-wave (16 waves) via LDS.
    #pragma unroll
    for (int off = 32; off > 0; off >>= 1) {
        const unsigned long long o = __shfl_down(best, off, 64);
        best = o < best ? o : best;
    }
    if ((tid & 63) == 0) wred[tid >> 6] = best;
    __syncthreads();

    if (tid == 0) {
        unsigned long long m = wred[0];
        #pragma unroll
        for (int wv = 1; wv < NTHR / 64; ++wv) {
            const unsigned long long o = wred[wv];
            m = o < m ? o : m;
        }
        s_win = (int)(m & 0xffffffffu);
    }
    __syncthreads();

    // Same block gathers: bit-exact copy of the winning window from global.
    if (tid < L_SZ)
        out[(size_t)b * L_SZ + tid] = X_in[(size_t)b * T_SZ + s_win + tid];
}

extern "C" void kernel_launch(void* const* d_in, const int* in_sizes, int n_in,
                              void* d_out, int out_size, void* d_ws, size_t ws_size,
                              hipStream_t stream) {
    // Input order: feats_in (unused), X_in, feats_out (unused), X_out
    const float* X_in  = (const float*)d_in[1];
    const float* X_out = (const float*)d_in[3];
    float* out = (float*)d_out;

    window_match_one<<<B_SZ, NTHR, 0, stream>>>(X_in, X_out, out);
}

// Round 4
// 79.025 us; speedup vs baseline: 2.1415x; 2.1415x over previous
//
#include <hip/hip_runtime.h>

// Problem constants: B=64, T=8192, L=64, NWIN=8128 = 8 * 1016
// Round-3 post-mortem: ALL prior versions were scratch-spill-bound
// (round 3: VGPR=64 with ~90 live -> 96 MB spill WRITE_SIZE, VALUBusy 1.3%).
// This version makes the hot loop's live set unspillable by construction:
// fully NAMED SCALARS (zero indexed arrays), 4 windows/thread, j chunked by 8
// -> ~35 VGPRs live. 512 blocks x 256 threads (2 blocks/CU). Linear LDS:
// the read pattern is stride-1 float4 per lane -> conflict-free, no swizzle.
// Single launch with the round-1-proven init-free agent-scope arrival-counter
// finish (old%8==7 fires exactly once per 8 increments for ANY start value).
constexpr int B_SZ  = 64;
constexpr int T_SZ  = 8192;
constexpr int L_SZ  = 64;
constexpr int NWIN  = T_SZ - L_SZ;   // 8128
constexpr int NQ    = 8;             // chunks per batch -> 512 blocks
constexpr int QW    = NWIN / NQ;     // 1016 windows per chunk
constexpr int STAGE = QW + L_SZ;     // 1080 floats staged (~4.3 KB)
constexpr int NTHR  = 256;
constexpr int WPT   = 4;             // 254 active threads * 4 = 1016 windows

#define STEP(ACC, XV, YV) { const float t_ = (XV) - (YV); ACC = fmaf(t_, t_, ACC); }
#define WIN8(ACC, A,B,C,D,E,F,G,H) \
    STEP(ACC, A, y0) STEP(ACC, B, y1) STEP(ACC, C, y2) STEP(ACC, D, y3) \
    STEP(ACC, E, y4) STEP(ACC, F, y5) STEP(ACC, G, y6) STEP(ACC, H, y7)

__global__ __launch_bounds__(NTHR, 2)
void window_match_fused(const float* __restrict__ X_in,
                        const float* __restrict__ X_out,
                        unsigned long long* __restrict__ ws_keys,
                        unsigned int* __restrict__ ws_cnt,
                        float* __restrict__ out)
{
    __shared__ float xs[STAGE];                // linear float4 layout
    __shared__ float ysh[L_SZ];
    __shared__ unsigned long long wred[NTHR / 64];
    __shared__ int s_win;

    const int bq   = blockIdx.x;
    const int b    = bq >> 3;
    const int q    = bq & 7;
    const int tid  = threadIdx.x;
    const int base = q * QW;                   // 1016*q, divisible by 4

    // Stage x[b, base .. base+1079]: 270 float4 over 256 threads (coalesced).
    const float4* xg  = reinterpret_cast<const float4*>(X_in + (size_t)b * T_SZ + base);
    float4*       xs4 = reinterpret_cast<float4*>(xs);
    xs4[tid] = xg[tid];
    if (tid < STAGE / 4 - NTHR)                // 14 threads do the tail
        xs4[tid + NTHR] = xg[tid + NTHR];
    if (tid < L_SZ) ysh[tid] = X_out[(size_t)b * L_SZ + tid];
    __syncthreads();

    unsigned long long best = ~0ull;
    if (tid < QW / WPT) {                      // tid < 254
        float a0 = 0.0f, a1 = 0.0f, a2 = 0.0f, a3 = 0.0f;
        const float4* xr = reinterpret_cast<const float4*>(xs);
        const float4* yr = reinterpret_cast<const float4*>(ysh);

        // j chunked by 8: per chunk 2 broadcast y-reads + 3 stride-1 b128
        // x-reads (floats [4*tid+8jc .. +8jc+11], windows need +10).
        #pragma unroll
        for (int jc = 0; jc < L_SZ / 8; ++jc) {
            const float4 ya = yr[2 * jc];
            const float4 yb = yr[2 * jc + 1];
            const float y0 = ya.x, y1 = ya.y, y2 = ya.z, y3 = ya.w;
            const float y4 = yb.x, y5 = yb.y, y6 = yb.z, y7 = yb.w;

            const float4 xa = xr[tid + 2 * jc];
            const float4 xb = xr[tid + 2 * jc + 1];
            const float4 xc = xr[tid + 2 * jc + 2];
            const float x0 = xa.x, x1 = xa.y, x2  = xa.z, x3  = xa.w;
            const float x4 = xb.x, x5 = xb.y, x6  = xb.z, x7  = xb.w;
            const float x8 = xc.x, x9 = xc.y, x10 = xc.z;

            WIN8(a0, x0, x1, x2, x3, x4, x5, x6, x7)
            WIN8(a1, x1, x2, x3, x4, x5, x6, x7, x8)
            WIN8(a2, x2, x3, x4, x5, x6, x7, x8, x9)
            WIN8(a3, x3, x4, x5, x6, x7, x8, x9, x10)
        }

        // Packed key: ((float_bits(d)<<32)|idx) — d>=0 so u64 order ==
        // (dist, idx) lexicographic, ties -> smallest index == np.argmin.
        const int g0 = base + WPT * tid;
        unsigned long long k0 = ((unsigned long long)__float_as_uint(a0) << 32) | (unsigned int)(g0 + 0);
        unsigned long long k1 = ((unsigned long long)__float_as_uint(a1) << 32) | (unsigned int)(g0 + 1);
        unsigned long long k2 = ((unsigned long long)__float_as_uint(a2) << 32) | (unsigned int)(g0 + 2);
        unsigned long long k3 = ((unsigned long long)__float_as_uint(a3) << 32) | (unsigned int)(g0 + 3);
        best = k0;
        best = k1 < best ? k1 : best;
        best = k2 < best ? k2 : best;
        best = k3 < best ? k3 : best;
    }

    // Wave (64-lane) shuffle reduce, then cross-wave (4 waves) via LDS.
    #pragma unroll
    for (int off = 32; off > 0; off >>= 1) {
        const unsigned long long o = __shfl_down(best, off, 64);
        best = o < best ? o : best;
    }
    if ((tid & 63) == 0) wred[tid >> 6] = best;
    __syncthreads();

    if (tid == 0) {
        unsigned long long m = wred[0];
        m = wred[1] < m ? wred[1] : m;
        m = wred[2] < m ? wred[2] : m;
        m = wred[3] < m ? wred[3] : m;

        // Publish key (agent scope = device-coherent across XCDs), then
        // arrival counter; 8th arriver (old%8==7, correct for any initial
        // value -> no workspace init) combines and selects the winner.
        __hip_atomic_store(&ws_keys[bq], m, __ATOMIC_RELEASE,
                           __HIP_MEMORY_SCOPE_AGENT);
        const unsigned int old = __hip_atomic_fetch_add(&ws_cnt[b], 1u,
                                                        __ATOMIC_ACQ_REL,
                                                        __HIP_MEMORY_SCOPE_AGENT);
        int sw = -1;
        if ((old & 7u) == 7u) {
            unsigned long long g = __hip_atomic_load(&ws_keys[b * NQ + 0],
                                                     __ATOMIC_ACQUIRE,
                                                     __HIP_MEMORY_SCOPE_AGENT);
            #pragma unroll
            for (int qq = 1; qq < NQ; ++qq) {
                const unsigned long long o = __hip_atomic_load(&ws_keys[b * NQ + qq],
                                                               __ATOMIC_ACQUIRE,
                                                               __HIP_MEMORY_SCOPE_AGENT);
                g = o < g ? o : g;
            }
            sw = (int)(g & 0xffffffffu);
        }
        s_win = sw;
    }
    __syncthreads();

    // Last-arriver block gathers: bit-exact copy of the winning window.
    const int s = s_win;
    if (s >= 0 && tid < L_SZ)
        out[(size_t)b * L_SZ + tid] = X_in[(size_t)b * T_SZ + s + tid];
}

extern "C" void kernel_launch(void* const* d_in, const int* in_sizes, int n_in,
                              void* d_out, int out_size, void* d_ws, size_t ws_size,
                              hipStream_t stream) {
    // Input order: feats_in (unused), X_in, feats_out (unused), X_out
    const float* X_in  = (const float*)d_in[1];
    const float* X_out = (const float*)d_in[3];
    float* out = (float*)d_out;
    unsigned long long* ws_keys = (unsigned long long*)d_ws;             // 512 * 8 B
    unsigned int* ws_cnt = (unsigned int*)((char*)d_ws + B_SZ * NQ * 8); // 64 * 4 B

    window_match_fused<<<B_SZ * NQ, NTHR, 0, stream>>>(X_in, X_out, ws_keys, ws_cnt, out);
}

// Round 5
// 64.932 us; speedup vs baseline: 2.6063x; 1.2170x over previous
//
#include <hip/hip_runtime.h>

// Problem constants: B=64, T=8192, L=64, NWIN=8128 = 8 * 1016
// Round-4 post-mortem: the spill-free inner loop (named scalars, ~35 VGPR) is
// proven, but a ~38 µs residue remained — shared only with round 1's kernel,
// whose one common structure was the agent-scope atomic finish (512 blocks x
// release-store + acq-rel RMW => per-block L2 writeback/invalidate on
// non-coherent XCD L2s). This version removes ALL device atomics: two
// launches. K1 (512 blocks) computes per-chunk best keys with the identical
// spill-free loop and plain-stores 512 u64 keys; kernel-boundary stream
// ordering makes them visible. K2 (64 blocks x 64 thr) min-reduces 8 keys per
// batch and gathers the winning window (bit-exact copy of input).
constexpr int B_SZ  = 64;
constexpr int T_SZ  = 8192;
constexpr int L_SZ  = 64;
constexpr int NWIN  = T_SZ - L_SZ;   // 8128
constexpr int NQ    = 8;             // chunks per batch -> 512 blocks
constexpr int QW    = NWIN / NQ;     // 1016 windows per chunk
constexpr int STAGE = QW + L_SZ;     // 1080 floats staged (~4.3 KB)
constexpr int NTHR  = 256;
constexpr int WPT   = 4;             // 254 active threads * 4 = 1016 windows

#define STEP(ACC, XV, YV) { const float t_ = (XV) - (YV); ACC = fmaf(t_, t_, ACC); }
#define WIN8(ACC, A,B,C,D,E,F,G,H) \
    STEP(ACC, A, y0) STEP(ACC, B, y1) STEP(ACC, C, y2) STEP(ACC, D, y3) \
    STEP(ACC, E, y4) STEP(ACC, F, y5) STEP(ACC, G, y6) STEP(ACC, H, y7)

__global__ __launch_bounds__(NTHR, 2)
void window_match_partial(const float* __restrict__ X_in,
                          const float* __restrict__ X_out,
                          unsigned long long* __restrict__ ws_keys)
{
    __shared__ float xs[STAGE];                // linear float4 layout
    __shared__ float ysh[L_SZ];
    __shared__ unsigned long long wred[NTHR / 64];

    const int bq   = blockIdx.x;
    const int b    = bq >> 3;
    const int q    = bq & 7;
    const int tid  = threadIdx.x;
    const int base = q * QW;                   // 1016*q, divisible by 4

    // Stage x[b, base .. base+1079]: 270 float4 over 256 threads (coalesced).
    const float4* xg  = reinterpret_cast<const float4*>(X_in + (size_t)b * T_SZ + base);
    float4*       xs4 = reinterpret_cast<float4*>(xs);
    xs4[tid] = xg[tid];
    if (tid < STAGE / 4 - NTHR)                // 14 threads do the tail
        xs4[tid + NTHR] = xg[tid + NTHR];
    if (tid < L_SZ) ysh[tid] = X_out[(size_t)b * L_SZ + tid];
    __syncthreads();

    unsigned long long best = ~0ull;
    if (tid < QW / WPT) {                      // tid < 254
        float a0 = 0.0f, a1 = 0.0f, a2 = 0.0f, a3 = 0.0f;
        const float4* xr = reinterpret_cast<const float4*>(xs);
        const float4* yr = reinterpret_cast<const float4*>(ysh);

        // j chunked by 8: per chunk 2 broadcast y-reads + 3 stride-1 b128
        // x-reads (floats [4*tid+8jc .. +8jc+11], windows need +10).
        // Live set: 4 acc + 11 x + 8 y + addressing ≈ 35 VGPRs — no spill.
        #pragma unroll
        for (int jc = 0; jc < L_SZ / 8; ++jc) {
            const float4 ya = yr[2 * jc];
            const float4 yb = yr[2 * jc + 1];
            const float y0 = ya.x, y1 = ya.y, y2 = ya.z, y3 = ya.w;
            const float y4 = yb.x, y5 = yb.y, y6 = yb.z, y7 = yb.w;

            const float4 xa = xr[tid + 2 * jc];
            const float4 xb = xr[tid + 2 * jc + 1];
            const float4 xc = xr[tid + 2 * jc + 2];
            const float x0 = xa.x, x1 = xa.y, x2  = xa.z, x3  = xa.w;
            const float x4 = xb.x, x5 = xb.y, x6  = xb.z, x7  = xb.w;
            const float x8 = xc.x, x9 = xc.y, x10 = xc.z;

            WIN8(a0, x0, x1, x2, x3, x4, x5, x6, x7)
            WIN8(a1, x1, x2, x3, x4, x5, x6, x7, x8)
            WIN8(a2, x2, x3, x4, x5, x6, x7, x8, x9)
            WIN8(a3, x3, x4, x5, x6, x7, x8, x9, x10)
        }

        // Packed key: ((float_bits(d)<<32)|idx) — d>=0 so u64 order ==
        // (dist, idx) lexicographic, ties -> smallest index == np.argmin.
        const int g0 = base + WPT * tid;
        unsigned long long k0 = ((unsigned long long)__float_as_uint(a0) << 32) | (unsigned int)(g0 + 0);
        unsigned long long k1 = ((unsigned long long)__float_as_uint(a1) << 32) | (unsigned int)(g0 + 1);
        unsigned long long k2 = ((unsigned long long)__float_as_uint(a2) << 32) | (unsigned int)(g0 + 2);
        unsigned long long k3 = ((unsigned long long)__float_as_uint(a3) << 32) | (unsigned int)(g0 + 3);
        best = k0;
        best = k1 < best ? k1 : best;
        best = k2 < best ? k2 : best;
        best = k3 < best ? k3 : best;
    }

    // Wave (64-lane) shuffle reduce, then cross-wave (4 waves) via LDS.
    #pragma unroll
    for (int off = 32; off > 0; off >>= 1) {
        const unsigned long long o = __shfl_down(best, off, 64);
        best = o < best ? o : best;
    }
    if ((tid & 63) == 0) wred[tid >> 6] = best;
    __syncthreads();

    if (tid == 0) {
        unsigned long long m = wred[0];
        m = wred[1] < m ? wred[1] : m;
        m = wred[2] < m ? wred[2] : m;
        m = wred[3] < m ? wred[3] : m;
        ws_keys[bq] = m;                       // plain store; kernel-end flush
    }
}

// K2: 64 blocks x 64 threads. All threads redundantly min-reduce the batch's
// 8 keys (broadcast loads, no sync) and copy the winning 64-float window.
__global__ __launch_bounds__(64)
void window_match_gather(const float* __restrict__ X_in,
                         const unsigned long long* __restrict__ ws_keys,
                         float* __restrict__ out)
{
    const int b   = blockIdx.x;
    const int tid = threadIdx.x;

    unsigned long long m = ws_keys[b * NQ + 0];
    #pragma unroll
    for (int qq = 1; qq < NQ; ++qq) {
        const unsigned long long o = ws_keys[b * NQ + qq];
        m = o < m ? o : m;
    }
    const int s = (int)(m & 0xffffffffu);
    out[(size_t)b * L_SZ + tid] = X_in[(size_t)b * T_SZ + s + tid];
}

extern "C" void kernel_launch(void* const* d_in, const int* in_sizes, int n_in,
                              void* d_out, int out_size, void* d_ws, size_t ws_size,
                              hipStream_t stream) {
    // Input order: feats_in (unused), X_in, feats_out (unused), X_out
    const float* X_in  = (const float*)d_in[1];
    const float* X_out = (const float*)d_in[3];
    float* out = (float*)d_out;
    unsigned long long* ws_keys = (unsigned long long*)d_ws;   // 512 * 8 B

    window_match_partial<<<B_SZ * NQ, NTHR, 0, stream>>>(X_in, X_out, ws_keys);
    window_match_gather<<<B_SZ, 64, 0, stream>>>(X_in, ws_keys, out);
}